// Round 1
// baseline (8447.850 us; speedup 1.0000x reference)
//
#include <hip/hip_runtime.h>
#include <hip/hip_bf16.h>

// ---------------------------------------------------------------------------
// MA_LSTM on MI355X (gfx950) — persistent-kernel version.
// All 128 timesteps run inside ONE kernel launch:
//   blocks 0..159  ("A"): z-GEMM, weights [kt|Wr^T|Wc^T] LDS-resident (144KB)
//   blocks 160..223("B"): gates (1 batch row each) + agg-GEMM (aggT LDS, 96KB)
// Device-scope split barriers (monotone counters + __threadfence).
// Grid 224 <= 256 CUs at 1 block/CU (LDS-limited) -> co-residency guaranteed,
// plain launch (graph-capture safe). __launch_bounds__(256,1).
// ---------------------------------------------------------------------------

typedef short  bf16x8 __attribute__((ext_vector_type(8)));
typedef float  f32x4  __attribute__((ext_vector_type(4)));
typedef __hip_bfloat16 bf16;

#define U 1024
#define BATCH 64
#define TSTEPS 128
#define DIM 256
#define N5 5120
#define K2 2048   // h(1024) + c(1024)

// ---- workspace layout (bytes) ----
#define OFF_WRC   0u                       // bf16 [5120][2048]  (Wr^T | Wc^T)
#define OFF_KT    20971520u                // bf16 [5120][256]   kernel^T
#define OFF_AGGT  23592960u                // bf16 [1024][3072]  aggregation^T
#define OFF_XBF   29884416u                // bf16 [64][128][256] x in bf16
#define OFF_Z     34078720u                // f32  [64][5120]
#define OFF_ABUF  35389440u                // bf16 [4][64][1024] h_hi,h_lo,c_hi,c_lo
#define OFF_C32   35913728u                // f32  [64][1024]
#define OFF_OBUF  36175872u                // bf16 [64][3072]
#define OFF_SCAL  36569088u                // f32  [8]
#define OFF_CTR   36569216u                // int barrier counters (512B zone)

#define NBLK_A 160
#define NBLK_B 64
#define NBLK   224

#define RS_A 4608   // LDS row stride bytes, A-role: 2304 bf16
#define RS_B 6144   // LDS row stride bytes, B-role: 3072 bf16

#define MFMA16(a,b,c) __builtin_amdgcn_mfma_f32_16x16x32_bf16((a),(b),(c),0,0,0)

// ---------------------------------------------------------------------------
// x: fp32 -> bf16, 4 elements/thread
__global__ __launch_bounds__(256) void k_xconv(const float* __restrict__ in,
                                               bf16* __restrict__ o, int n4) {
    const int i = blockIdx.x * 256 + threadIdx.x;
    if (i < n4) {
        const float4 v = ((const float4*)in)[i];
        bf16 tmp[4] = {__float2bfloat16(v.x), __float2bfloat16(v.y),
                       __float2bfloat16(v.z), __float2bfloat16(v.w)};
        ((uint2*)o)[i] = *(const uint2*)tmp;
    }
}

// ---------------------------------------------------------------------------
// tiled transpose + fp32->bf16: out[c*out_stride + out_off + r] = bf16(in[r*C+c])
__global__ __launch_bounds__(256) void k_transpose(const float* __restrict__ in,
                                                   bf16* __restrict__ out,
                                                   int C, int out_stride, int out_off) {
    __shared__ bf16 tile[64][65];
    const int tc = blockIdx.x * 64, tr = blockIdx.y * 64;
    const int tx = threadIdx.x & 63, ty0 = threadIdx.x >> 6;
#pragma unroll
    for (int i = 0; i < 64; i += 4)
        tile[ty0 + i][tx] = __float2bfloat16(in[(tr + ty0 + i) * C + tc + tx]);
    __syncthreads();
#pragma unroll
    for (int i = 0; i < 64; i += 4)
        out[(tc + ty0 + i) * out_stride + out_off + tr + tx] = tile[tx][ty0 + i];
}

// ---------------------------------------------------------------------------
struct AttPtrs { const float* p[12]; };

__global__ __launch_bounds__(256) void k_scal(AttPtrs ap, float* __restrict__ scal) {
    __shared__ float red[256];
    const int tid = threadIdx.x;
    for (int q = 0; q < 6; ++q) {
        const float* l = ap.p[2 * q];
        const float* r = ap.p[2 * q + 1];
        float s = 0.f;
        for (int i = tid; i < 1024; i += 256)
            s += l[i] * r[i];
        red[tid] = s; __syncthreads();
        for (int o = 128; o > 0; o >>= 1) {
            if (tid < o) red[tid] += red[tid + o];
            __syncthreads();
        }
        if (tid == 0) scal[q] = red[0];
        __syncthreads();
    }
}

// ---------------------------------------------------------------------------
// block collectives (256 threads = 4 waves)
__device__ __forceinline__ float wave_sum(float v) {
#pragma unroll
    for (int o = 32; o > 0; o >>= 1) v += __shfl_xor(v, o, 64);
    return v;
}
__device__ __forceinline__ float wave_max(float v) {
#pragma unroll
    for (int o = 32; o > 0; o >>= 1) v = fmaxf(v, __shfl_xor(v, o, 64));
    return v;
}
__device__ __forceinline__ float wave_scan(float v, int lane) {
#pragma unroll
    for (int o = 1; o < 64; o <<= 1) {
        float n = __shfl_up(v, o, 64);
        if (lane >= o) v += n;
    }
    return v;
}
__device__ __forceinline__ float block_sum(float v, float* sm4, int w, int lane) {
    float s = wave_sum(v);
    if (lane == 0) sm4[w] = s;
    __syncthreads();
    float r = sm4[0] + sm4[1] + sm4[2] + sm4[3];
    __syncthreads();
    return r;
}
__device__ __forceinline__ float block_max(float v, float* sm4, int w, int lane) {
    float s = wave_max(v);
    if (lane == 0) sm4[w] = s;
    __syncthreads();
    float r = fmaxf(fmaxf(sm4[0], sm4[1]), fmaxf(sm4[2], sm4[3]));
    __syncthreads();
    return r;
}
__device__ __forceinline__ float block_scan(float v, float* sm4, int w, int lane, float* total) {
    float ws = wave_scan(v, lane);
    if (lane == 63) sm4[w] = ws;
    __syncthreads();
    float base = 0.f;
    if (w > 0) base += sm4[0];
    if (w > 1) base += sm4[1];
    if (w > 2) base += sm4[2];
    *total = sm4[0] + sm4[1] + sm4[2] + sm4[3];
    __syncthreads();
    return base + ws;
}
__device__ __forceinline__ float sigm(float x) { return 1.f / (1.f + __expf(-x)); }

// ---------------------------------------------------------------------------
// device-scope split barriers: monotone counters, reset per-launch via memset.
// signal: all block work done -> fence -> single atomicAdd (fire & forget).
// wait:   tid0 spins (relaxed) until counter >= target, then acquire fence.
__device__ __forceinline__ void bar_signal(int* c) {
    __syncthreads();
    if (threadIdx.x == 0) {
        __threadfence();   // release: publish this block's global writes
        __hip_atomic_fetch_add(c, 1, __ATOMIC_RELEASE, __HIP_MEMORY_SCOPE_AGENT);
    }
}
__device__ __forceinline__ void bar_wait(int* c, int target) {
    if (threadIdx.x == 0) {
        while (__hip_atomic_load(c, __ATOMIC_RELAXED, __HIP_MEMORY_SCOPE_AGENT) < target)
            __builtin_amdgcn_s_sleep(1);
        __threadfence();   // acquire: invalidate stale L1/L2 before data reads
    }
    __syncthreads();
}

// swizzled LDS read (T2-style XOR: spreads 8 consecutive rows over 8 16B slots,
// turns the stride-4608/6144 16-way bank conflict into free <=2-way)
__device__ __forceinline__ bf16x8 lds_rd(const char* s, int nloc, int kb, int rs) {
    return *(const bf16x8*)(s + nloc * rs + (kb ^ ((nloc & 7) << 4)));
}

// ---------------------------------------------------------------------------
__global__ __launch_bounds__(256, 1) void k_persist(
    const bf16* __restrict__ xbf, const bf16* __restrict__ kt,
    const bf16* __restrict__ wrct, const bf16* __restrict__ aggt,
    float* __restrict__ zbuf, bf16* __restrict__ abuf,
    float* __restrict__ c32, bf16* __restrict__ obuf,
    const float* __restrict__ scal, const float* __restrict__ bias,
    float* __restrict__ out, int* __restrict__ ctr)
{
    __shared__ __align__(16) char smem[147456];   // 144KB weight tile (role A)
    __shared__ float sm4[4];

    const int bid = blockIdx.x, tid = threadIdx.x;
    const int w = tid >> 6, lane = tid & 63;
    const int ml = lane & 15, q = lane >> 4;
    int* S1 = ctr;        // z ready        (A arrives, B waits)   -> 160*(t+1)
    int* S2 = ctr + 32;   // O ready        (B internal)           ->  64*(t+1)
    int* S3 = ctr + 64;   // h,c ready      (B arrives, A waits)   ->  64*(t+1)

    if (bid < NBLK_A) {
        // =================== role A: z-GEMM, 32 n-cols ====================
        const int n0 = bid * 32;
        // stage [kt|wrct] tile into swizzled LDS: [32][2304] bf16
        for (int i = 0; i < 36; ++i) {
            int cid = i * 256 + tid;          // 0..9215
            int nloc = cid / 288, kc = cid - nloc * 288;
            int k = kc * 8;
            bf16x8 v;
            if (k < 256) v = *(const bf16x8*)(kt + (n0 + nloc) * DIM + k);
            else         v = *(const bf16x8*)(wrct + (n0 + nloc) * K2 + (k - 256));
            *(bf16x8*)(smem + nloc * RS_A + ((k * 2) ^ ((nloc & 7) << 4))) = v;
        }
        __syncthreads();

        const float biasA = bias[n0 + ml];
        const float biasB = bias[n0 + 16 + ml];
        const int rowA = w * 16 + ml;          // this lane's A-frag row (batch)
        const bf16* hHi = abuf + 0 * 65536 + rowA * U;
        const bf16* hLo = abuf + 1 * 65536 + rowA * U;
        const bf16* cHi = abuf + 2 * 65536 + rowA * U;
        const bf16* cLo = abuf + 3 * 65536 + rowA * U;
        const bf16* xrow0 = xbf + rowA * (TSTEPS * DIM);

#define LOADG(G, BUF) do { _Pragma("unroll") \
        for (int j_ = 0; j_ < 4; ++j_) { \
            const int ch_ = (G) * 4 + j_; \
            const int kk_ = ((ch_ < 32) ? ch_ : ch_ - 32) * 32 + q * 8; \
            bh[BUF][j_] = *(const bf16x8*)(((ch_ < 32) ? hHi : cHi) + kk_); \
            bl[BUF][j_] = *(const bf16x8*)(((ch_ < 32) ? hLo : cLo) + kk_); \
        } } while (0)

        for (int t = 0; t < TSTEPS; ++t) {
            f32x4 acc0 = {0.f, 0.f, 0.f, 0.f}, acc1 = {0.f, 0.f, 0.f, 0.f};
            // ---- x @ kernel part: independent of h,c -> run BEFORE S3 wait
            {
                const bf16* xr = xrow0 + t * DIM + q * 8;
                bf16x8 ax[8];
#pragma unroll
                for (int ch = 0; ch < 8; ++ch) ax[ch] = *(const bf16x8*)(xr + ch * 32);
#pragma unroll
                for (int ch = 0; ch < 8; ++ch) {
                    const int kb = ch * 64 + q * 16;
                    const bf16x8 b0 = lds_rd(smem, ml, kb, RS_A);
                    const bf16x8 b1 = lds_rd(smem, 16 + ml, kb, RS_A);
                    acc0 = MFMA16(ax[ch], b0, acc0);
                    acc1 = MFMA16(ax[ch], b1, acc1);
                }
            }
            bar_wait(S3, NBLK_B * t);          // h,c of step t-1 ready
            // ---- (h|c) hi/lo part: 64 chunks, groups of 4, 2-group prefetch
            {
                bf16x8 bh[3][4], bl[3][4];
                LOADG(0, 0);
                LOADG(1, 1);
#pragma unroll
                for (int g = 0; g < 16; ++g) {
                    if (g < 14) LOADG(g + 2, (g + 2) % 3);
#pragma unroll
                    for (int j = 0; j < 4; ++j) {
                        const int ch = g * 4 + j;
                        const int kb = 512 + ch * 64 + q * 16;  // LDS k offset
                        const bf16x8 b0 = lds_rd(smem, ml, kb, RS_A);
                        const bf16x8 b1 = lds_rd(smem, 16 + ml, kb, RS_A);
                        const int B_ = g % 3;
                        acc0 = MFMA16(bh[B_][j], b0, acc0);
                        acc1 = MFMA16(bh[B_][j], b1, acc1);
                        acc0 = MFMA16(bl[B_][j], b0, acc0);
                        acc1 = MFMA16(bl[B_][j], b1, acc1);
                    }
                }
            }
            // ---- epilogue: z = acc + bias
            {
                const int r0 = w * 16 + q * 4;
#pragma unroll
                for (int r = 0; r < 4; ++r) {
                    zbuf[(r0 + r) * N5 + n0 + ml]      = acc0[r] + biasA;
                    zbuf[(r0 + r) * N5 + n0 + 16 + ml] = acc1[r] + biasB;
                }
            }
            bar_signal(S1);
        }
#undef LOADG
    } else {
        // ============ role B: gates (row rb) + agg-GEMM (16 u-cols) ============
        const int rb = bid - NBLK_A;
        const int n0 = rb * 16;
        // stage aggT tile into swizzled LDS: [16][3072] bf16
        for (int i = 0; i < 24; ++i) {
            int cid = i * 256 + tid;          // 0..6143
            int nloc = cid / 384, kc = cid - nloc * 384;
            int k = kc * 8;
            bf16x8 v = *(const bf16x8*)(aggt + (n0 + nloc) * 3072 + k);
            *(bf16x8*)(smem + nloc * RS_B + ((k * 2) ^ ((nloc & 7) << 4))) = v;
        }
        __syncthreads();

        const float s_ud = scal[0], s_ur = scal[1], s_ru = scal[2],
                    s_rd = scal[3], s_du = scal[4], s_dr = scal[5];
        const int rowA = w * 16 + ml;
        const bf16* orow = obuf + rowA * 3072;

#define LOADO(G, BUF) do { _Pragma("unroll") \
        for (int j_ = 0; j_ < 8; ++j_) \
            ob[BUF][j_] = *(const bf16x8*)(orow + ((G) * 8 + j_) * 32 + q * 8); \
        } while (0)

        for (int t = 0; t < TSTEPS; ++t) {
            bar_wait(S1, NBLK_A * (t + 1));    // z of step t ready
            // ---------------- P2: gates for batch row rb ----------------
            {
                const float* zr = zbuf + rb * N5;
                const float4 zu = ((const float4*)zr)[tid];
                const float4 zd = ((const float4*)(zr + U))[tid];
                const float4 zn = ((const float4*)(zr + 2 * U))[tid];

                float mup = block_max(fmaxf(fmaxf(zu.x, zu.y), fmaxf(zu.z, zu.w)), sm4, w, lane);
                const float e0 = __expf(zu.x - mup), e1 = __expf(zu.y - mup),
                            e2 = __expf(zu.z - mup), e3 = __expf(zu.w - mup);
                float totu;
                float inclu = block_scan(e0 + e1 + e2 + e3, sm4, w, lane, &totu);
                const float exclu = inclu - (e0 + e1 + e2 + e3);
                const float inv_u = 1.f / totu;
                const float u0 = (exclu + e0) * inv_u;
                const float u1 = (exclu + e0 + e1) * inv_u;
                const float u2 = (exclu + e0 + e1 + e2) * inv_u;
                const float u3 = (exclu + e0 + e1 + e2 + e3) * inv_u;

                float mdn = block_max(fmaxf(fmaxf(zd.x, zd.y), fmaxf(zd.z, zd.w)), sm4, w, lane);
                const float f0 = __expf(zd.x - mdn), f1 = __expf(zd.y - mdn),
                            f2 = __expf(zd.z - mdn), f3 = __expf(zd.w - mdn);
                float totd;
                float incld = block_scan(f0 + f1 + f2 + f3, sm4, w, lane, &totd);
                const float excld = incld - (f0 + f1 + f2 + f3);
                const float inv_d = 1.f / totd;
                const float d0 = (totd - excld) * inv_d;
                const float d1 = (totd - excld - f0) * inv_d;
                const float d2 = (totd - excld - f0 - f1) * inv_d;
                const float d3 = (totd - excld - f0 - f1 - f2) * inv_d;

                const float du = block_sum(d0 * u0 + d1 * u1 + d2 * u2 + d3 * u3, sm4, w, lane);
                const float ru = block_sum(zn.x * u0 + zn.y * u1 + zn.z * u2 + zn.w * u3, sm4, w, lane);
                const float dr = block_sum(d0 * zn.x + d1 * zn.y + d2 * zn.z + d3 * zn.w, sm4, w, lane);

                bf16* orw = obuf + rb * 3072;
                const int j0 = tid * 4;
                const float uu[4] = {u0, u1, u2, u3};
                const float dd[4] = {d0, d1, d2, d3};
                const float rr[4] = {zn.x, zn.y, zn.z, zn.w};
                bf16 t1[4], t2[4], t3[4];
#pragma unroll
                for (int i = 0; i < 4; ++i) {
                    t1[i] = __float2bfloat16(sigm(s_ud * uu[i] * du) + sigm(s_ur * uu[i] * ru));
                    t2[i] = __float2bfloat16(sigm(s_ru * rr[i] * ru) + sigm(s_rd * rr[i] * dr));
                    t3[i] = __float2bfloat16(sigm(s_du * dd[i] * du) + sigm(s_dr * dd[i] * dr));
                }
                *(uint2*)(orw + j0)         = *(uint2*)t1;
                *(uint2*)(orw + U + j0)     = *(uint2*)t2;
                *(uint2*)(orw + 2 * U + j0) = *(uint2*)t3;
            }
            bar_signal(S2);
            bar_wait(S2, NBLK_B * (t + 1));    // all O rows ready
            // -------- P3: f = sigm(O@agg); state update; emit out --------
            {
                f32x4 p0 = {0.f, 0.f, 0.f, 0.f}, p1 = {0.f, 0.f, 0.f, 0.f};
                bf16x8 ob[4][8];
                LOADO(0, 0);
                LOADO(1, 1);
                LOADO(2, 2);
#pragma unroll
                for (int g = 0; g < 12; ++g) {
                    if (g < 9) LOADO(g + 3, (g + 3) & 3);
#pragma unroll
                    for (int j = 0; j < 8; ++j) {
                        const int ch = g * 8 + j;
                        const int kb = ch * 64 + q * 16;
                        const bf16x8 b = lds_rd(smem, ml, kb, RS_B);
                        if (j & 1) p1 = MFMA16(ob[g & 3][j], b, p1);
                        else       p0 = MFMA16(ob[g & 3][j], b, p0);
                    }
                }
                const f32x4 accv = p0 + p1;
                const int col = n0 + ml;
                const int r0 = w * 16 + q * 4;
#pragma unroll
                for (int r = 0; r < 4; ++r) {
                    const int row = r0 + r;
                    const float f = sigm(accv[r]);
                    const float cold = c32[row * U + col];
                    const float z3 = zbuf[row * N5 + 3 * U + col];
                    const float z4 = zbuf[row * N5 + 4 * U + col];
                    const float cn = f * cold + (1.f - f) * tanhf(z4);
                    const float hn = z3 * tanhf(cn);
                    c32[row * U + col] = cn;
                    const bf16 chb = __float2bfloat16(cn);
                    const bf16 clb = __float2bfloat16(cn - __bfloat162float(chb));
                    const bf16 hhb = __float2bfloat16(hn);
                    const bf16 hlb = __float2bfloat16(hn - __bfloat162float(hhb));
                    abuf[0 * 65536 + row * U + col] = hhb;
                    abuf[1 * 65536 + row * U + col] = hlb;
                    abuf[2 * 65536 + row * U + col] = chb;
                    abuf[3 * 65536 + row * U + col] = clb;
                    out[(row * TSTEPS + t) * U + col] = hn;
                }
            }
            bar_signal(S3);
        }
#undef LOADO
    }
}

// ---------------------------------------------------------------------------
extern "C" void kernel_launch(void* const* d_in, const int* in_sizes, int n_in,
                              void* d_out, int out_size, void* d_ws, size_t ws_size,
                              hipStream_t stream) {
    (void)in_sizes; (void)n_in; (void)out_size; (void)ws_size;
    const float* x    = (const float*)d_in[0];
    const float* Wk   = (const float*)d_in[1];   // (256,5120)
    const float* Wr   = (const float*)d_in[2];   // (1024,5120)
    const float* Wc   = (const float*)d_in[3];   // (1024,5120)
    const float* bias = (const float*)d_in[4];   // (5120)
    const float* agg  = (const float*)d_in[5];   // (3072,1024)

    char* ws = (char*)d_ws;
    bf16*  wrct = (bf16*)(ws + OFF_WRC);
    bf16*  kt   = (bf16*)(ws + OFF_KT);
    bf16*  aggt = (bf16*)(ws + OFF_AGGT);
    bf16*  xbf  = (bf16*)(ws + OFF_XBF);
    float* zbuf = (float*)(ws + OFF_Z);
    bf16*  abuf = (bf16*)(ws + OFF_ABUF);
    float* c32  = (float*)(ws + OFF_C32);
    bf16*  obuf = (bf16*)(ws + OFF_OBUF);
    float* scal = (float*)(ws + OFF_SCAL);
    int*   ctr  = (int*)(ws + OFF_CTR);
    float* out  = (float*)d_out;

    hipMemsetAsync(abuf, 0, 4 * 65536 * sizeof(bf16), stream);
    hipMemsetAsync(c32, 0, BATCH * U * sizeof(float), stream);
    hipMemsetAsync(ctr, 0, 512, stream);   // barrier counters reset each launch

    // one-time conversions / transposes
    k_xconv<<<(BATCH * TSTEPS * DIM / 4 + 255) / 256, 256, 0, stream>>>(x, xbf, BATCH * TSTEPS * DIM / 4);
    k_transpose<<<dim3(5120 / 64, 1024 / 64), 256, 0, stream>>>(Wr, wrct, 5120, 2048, 0);
    k_transpose<<<dim3(5120 / 64, 1024 / 64), 256, 0, stream>>>(Wc, wrct, 5120, 2048, 1024);
    k_transpose<<<dim3(5120 / 64, 256 / 64),  256, 0, stream>>>(Wk, kt,   5120, 256, 0);
    k_transpose<<<dim3(1024 / 64, 3072 / 64), 256, 0, stream>>>(agg, aggt, 1024, 3072, 0);

    AttPtrs ap;
    for (int i = 0; i < 12; ++i) ap.p[i] = (const float*)d_in[6 + i];
    k_scal<<<1, 256, 0, stream>>>(ap, scal);

    // the whole recurrence: one persistent launch
    k_persist<<<NBLK, 256, 0, stream>>>(xbf, kt, wrct, aggt, zbuf, abuf, c32,
                                        obuf, scal, bias, out, ctr);
}